// Round 8
// baseline (987.640 us; speedup 1.0000x reference)
//
#include <hip/hip_runtime.h>
#include <hip/hip_bf16.h>

#define BB 32
#define TT 2048
#define JJ 256
#define DD 256

// PROBE: P1 body repeated inside one dispatch so it clears the top-5 cutoff
// (fills are ~190-208us; single P1 ~95us is invisible). Idempotent per rep.
#define P1_REPS 3

typedef __attribute__((ext_vector_type(4))) float f32x4;
typedef __attribute__((ext_vector_type(8))) short bf16x8;
typedef __attribute__((ext_vector_type(2))) unsigned int u32x2v;

static __device__ __forceinline__ unsigned short f2bf(float x) {
    unsigned u = __builtin_bit_cast(unsigned, x);
    u = (u + 0x7fffu + ((u >> 16) & 1u)) >> 16;
    return (unsigned short)u;
}
static __device__ __forceinline__ unsigned pack2(float a, float b) {
    return (unsigned)f2bf(a) | ((unsigned)f2bf(b) << 16);
}

// async 16B global->LDS stage of one 256-row x 32-k bf16 B-slice (16KB), chunk-XOR-swizzled.
static __device__ __forceinline__ void stage_slice(
    const unsigned short* __restrict__ Bsrc, char* pool, int buf, int kt, int tid, int wid)
{
    #pragma unroll
    for (int it = 0; it < 4; ++it) {
        int s = it * 256 + tid;              // 16B-slot index 0..1023
        int row = s >> 2, cp = s & 3;
        int c = cp ^ (row & 3);              // involution: pre-swizzled global source
        const char* src = (const char*)Bsrc + row * 512 + kt * 64 + c * 16;
        __builtin_amdgcn_global_load_lds(
            (const __attribute__((address_space(1))) unsigned int*)src,
            (__attribute__((address_space(3))) unsigned int*)(pool + (buf << 14) + (it << 12) + (wid << 10)),
            16, 0, 0);
    }
}

// ---------------- P0: U -> Ubf (row-major bf16), UbfT (transposed bf16), Uw = U.w_u (f32)
__global__ __launch_bounds__(256) void p0_prep(
    const float* __restrict__ U, const float* __restrict__ w,
    unsigned short* __restrict__ Ubf, unsigned short* __restrict__ UbfT,
    float* __restrict__ Uw)
{
    const int b = blockIdx.x >> 2, jc = blockIdx.x & 3;
    const int tid = threadIdx.x;
    __shared__ unsigned short lt[64][258];
    const f32x4* U4 = (const f32x4*)U;
    const f32x4* W4 = (const f32x4*)w;
    for (int it = 0; it < 16; ++it) {
        int fi = it * 256 + tid;
        int lr = fi >> 6, c4 = fi & 63;
        int j = b * 256 + jc * 64 + lr;
        f32x4 u4 = U4[j * 64 + c4];
        unsigned short s0 = f2bf(u4[0]), s1 = f2bf(u4[1]), s2 = f2bf(u4[2]), s3 = f2bf(u4[3]);
        u32x2v pk; pk[0] = (unsigned)s0 | ((unsigned)s1 << 16); pk[1] = (unsigned)s2 | ((unsigned)s3 << 16);
        *(u32x2v*)(Ubf + j * 256 + c4 * 4) = pk;
        lt[lr][c4*4+0] = s0; lt[lr][c4*4+1] = s1; lt[lr][c4*4+2] = s2; lt[lr][c4*4+3] = s3;
        f32x4 wu = W4[64 + c4];
        float p = u4[0]*wu[0] + u4[1]*wu[1] + u4[2]*wu[2] + u4[3]*wu[3];
        #pragma unroll
        for (int o = 32; o; o >>= 1) p += __shfl_xor(p, o);
        if ((tid & 63) == 0) Uw[j] = p;
    }
    __syncthreads();
    for (int it2 = 0; it2 < 64; ++it2) {
        int d = it2 * 4 + (tid >> 6);
        int jl = tid & 63;
        UbfT[(b * 256 + d) * 256 + jc * 64 + jl] = lt[jl][d];
    }
}

// ---------------- P1: fused S -> masked softmax -> c2q; writes c2q, G0, G1, G2, mb
// EXACT round-3 structure; body wrapped in P1_REPS probe loop (idempotent).
__global__ __launch_bounds__(256, 3) void p1_main(
    const float* __restrict__ H, const float* __restrict__ Um,
    const float* __restrict__ w, const float* __restrict__ biasp,
    const unsigned short* __restrict__ Ubf, const unsigned short* __restrict__ UbfT,
    const float* __restrict__ Uw,
    float* __restrict__ mb, float* __restrict__ Gout, float* __restrict__ c2q_out)
{
    // XCD-bijective swizzle: 1024 blocks = 8 XCDs x 128; each XCD owns 4 batches
    const int id = blockIdx.x;
    const int n = ((id & 7) << 7) | (id >> 3);
    const int b = n >> 5, tb = n & 31;
    const int t0 = tb * 64;
    const int tid = threadIdx.x;
    const int wid = tid >> 6, lane = tid & 63, g = lane >> 4, l16 = lane & 15;

    // pool phases: [hw 32KB] -> [B dbuf 2x16KB] -> [p_lds 4x9216] -> [B dbuf]
    __shared__ __align__(16) char pool[36864];
    __shared__ float uw_lds[256];
    __shared__ float um_lds[256];
    __shared__ float rt_lds[64];

    const f32x4* H4 = (const f32x4*)H;
    const f32x4* W4 = (const f32x4*)w;
    f32x4* G4 = (f32x4*)Gout;
    const float bias = biasp[0];
    const unsigned short* Ubf_b  = Ubf  + (size_t)b * 65536;
    const unsigned short* UbfT_b = UbfT + (size_t)b * 65536;

    uw_lds[tid] = Uw[b * 256 + tid];
    um_lds[tid] = Um[b * 256 + tid];

    #pragma unroll 1
    for (int rep = 0; rep < P1_REPS; ++rep) {

    // Phase A: stage Hw = H*w_hu into LDS (bf16, XOR-swizzled rows); rowterm = H.w_h; G0 = H
    for (int it = 0; it < 16; ++it) {
        int fi = it * 256 + tid;
        int lr = fi >> 6, c4 = fi & 63;
        f32x4 h4 = H4[(b * TT + t0 + lr) * 64 + c4];
        f32x4 whu = W4[128 + c4];
        f32x4 wh = W4[c4];
        G4[(b * TT + t0 + lr) * 256 + c4] = h4;          // G0 = H (coalesced f32x4)
        f32x4 hw = h4 * whu;
        u32x2v pk; pk[0] = pack2(hw[0], hw[1]); pk[1] = pack2(hw[2], hw[3]);
        unsigned off = ((unsigned)(lr * 512 + c4 * 8)) ^ ((unsigned)((lr & 7) << 4));
        *(u32x2v*)(pool + off) = pk;
        float p = h4[0]*wh[0] + h4[1]*wh[1] + h4[2]*wh[2] + h4[3]*wh[3];
        #pragma unroll
        for (int o = 32; o; o >>= 1) p += __shfl_xor(p, o);
        if (lane == 0) rt_lds[lr] = p;
    }
    __syncthreads();

    // A-frags (Hw rows of this wave) into registers
    bf16x8 af[8];
    {
        const int row = wid * 16 + l16;
        #pragma unroll
        for (int kt = 0; kt < 8; ++kt) {
            unsigned off = ((unsigned)(row * 512 + kt * 64 + g * 16)) ^ ((unsigned)((row & 7) << 4));
            af[kt] = *(const bf16x8*)(pool + off);
        }
    }
    __syncthreads();   // hw dead -> pool reused for B double-buffer

    // matmul1: S-core[t][j]; B = Ubf slices LDS-staged, double-buffered
    f32x4 acc[16];
    #pragma unroll
    for (int nt = 0; nt < 16; ++nt) acc[nt] = (f32x4)(0.0f);
    stage_slice(Ubf_b, pool, 0, 0, tid, wid);
    __syncthreads();                       // slice 0 resident
    #pragma unroll
    for (int kt = 0; kt < 8; ++kt) {
        if (kt < 7) stage_slice(Ubf_b, pool, (kt + 1) & 1, kt + 1, tid, wid);
        const char* bufp = pool + ((kt & 1) << 14);
        #pragma unroll
        for (int nt = 0; nt < 16; ++nt) {
            const int row = nt * 16 + l16;
            bf16x8 bfr = *(const bf16x8*)(bufp + row * 64 + ((g ^ (row & 3)) << 4));
            acc[nt] = __builtin_amdgcn_mfma_f32_16x16x32_bf16(af[kt], bfr, acc[nt], 0, 0, 0);
        }
        __syncthreads();                   // drains next-slice stage + compute reads
    }

    // masked softmax over j (rowterm+bias are shift-invariant; added only to mb)
    float rmax[4] = {-3e38f, -3e38f, -3e38f, -3e38f};
    #pragma unroll
    for (int nt = 0; nt < 16; ++nt) {
        float ct = uw_lds[nt * 16 + l16];
        float msk = um_lds[nt * 16 + l16];
        #pragma unroll
        for (int r = 0; r < 4; ++r) {
            float v = acc[nt][r] + ct;
            acc[nt][r] = v;
            if (msk > 0.5f) rmax[r] = fmaxf(rmax[r], v);
        }
    }
    #pragma unroll
    for (int r = 0; r < 4; ++r) {
        #pragma unroll
        for (int o = 1; o < 16; o <<= 1) rmax[r] = fmaxf(rmax[r], __shfl_xor(rmax[r], o));
    }
    float rsum[4] = {0.f, 0.f, 0.f, 0.f};
    #pragma unroll
    for (int nt = 0; nt < 16; ++nt) {
        float msk = um_lds[nt * 16 + l16];
        #pragma unroll
        for (int r = 0; r < 4; ++r) {
            float e = (msk > 0.5f) ? exp2f((acc[nt][r] - rmax[r]) * 1.44269504f) : 0.0f;
            acc[nt][r] = e;
            rsum[r] += e;
        }
    }
    #pragma unroll
    for (int r = 0; r < 4; ++r) {
        #pragma unroll
        for (int o = 1; o < 16; o <<= 1) rsum[r] += __shfl_xor(rsum[r], o);
    }
    if (l16 == 0) {
        #pragma unroll
        for (int r = 0; r < 4; ++r) {
            int lrow = wid * 16 + g * 4 + r;
            mb[b * TT + t0 + lrow] = rmax[r] + rt_lds[lrow] + bias;
        }
    }
    float inv[4];
    #pragma unroll
    for (int r = 0; r < 4; ++r) inv[r] = 1.0f / rsum[r];

    // write P^T to LDS: p_lds[wave][j][t], 36B j-rows (9j mod 32 is a permutation -> ~conflict-free)
    const unsigned wb = (unsigned)wid * 9216u;
    #pragma unroll
    for (int nt = 0; nt < 16; ++nt) {
        int j = nt * 16 + l16;
        unsigned lo = pack2(acc[nt][0] * inv[0], acc[nt][1] * inv[1]);
        unsigned hi = pack2(acc[nt][2] * inv[2], acc[nt][3] * inv[3]);
        char* p = pool + wb + (unsigned)(j * 36) + (unsigned)(g * 8);
        *(unsigned*)(p) = lo;
        *(unsigned*)(p + 4) = hi;
    }
    // per-wave region: no barrier needed between own writes and own reads (lgkm ordering)
    bf16x8 pa[8];
    #pragma unroll
    for (int kt = 0; kt < 8; ++kt) {
        #pragma unroll
        for (int jj = 0; jj < 8; ++jj) {
            int j = kt * 32 + g * 8 + jj;
            unsigned short pv = *(const unsigned short*)(pool + wb + (unsigned)(j * 36) + (unsigned)(l16 * 2));
            pa[kt][jj] = (short)pv;
        }
    }
    __syncthreads();   // all pa extracted -> pool reusable for B double-buffer

    // matmul2: c2q[t][d]; B = UbfT slices LDS-staged, double-buffered
    f32x4 acc2[16];
    #pragma unroll
    for (int nt = 0; nt < 16; ++nt) acc2[nt] = (f32x4)(0.0f);
    stage_slice(UbfT_b, pool, 0, 0, tid, wid);
    __syncthreads();
    #pragma unroll
    for (int kt = 0; kt < 8; ++kt) {
        if (kt < 7) stage_slice(UbfT_b, pool, (kt + 1) & 1, kt + 1, tid, wid);
        const char* bufp = pool + ((kt & 1) << 14);
        #pragma unroll
        for (int nt = 0; nt < 16; ++nt) {
            const int row = nt * 16 + l16;
            bf16x8 bfr = *(const bf16x8*)(bufp + row * 64 + ((g ^ (row & 3)) << 4));
            acc2[nt] = __builtin_amdgcn_mfma_f32_16x16x32_bf16(pa[kt], bfr, acc2[nt], 0, 0, 0);
        }
        __syncthreads();
    }

    // epilogue: c2q, G1 = c2q, G2 = H*c2q (round-3 scalar form, plain stores)
    #pragma unroll
    for (int nt = 0; nt < 16; ++nt) {
        int d = nt * 16 + l16;
        #pragma unroll
        for (int r = 0; r < 4; ++r) {
            int t = t0 + wid * 16 + g * 4 + r;
            float c = acc2[nt][r];
            float h = H[(b * TT + t) * 256 + d];
            int gbase = (b * TT + t) * 1024;
            Gout[gbase + 256 + d] = c;
            Gout[gbase + 512 + d] = h * c;
            c2q_out[(b * TT + t) * 256 + d] = c;
        }
    }
    __syncthreads();   // rep isolation: next rep's phase-A LDS writes

    } // rep
}

// ---------------- P2a: b_vec = masked softmax(mb, H_mask); zero q2c
__global__ __launch_bounds__(256) void p2a_bvec(
    const float* __restrict__ mb, const float* __restrict__ Hm,
    float* __restrict__ bvec, float* __restrict__ q2c_out)
{
    const int b = blockIdx.x, tid = threadIdx.x;
    __shared__ float red[8];
    float mv[8], hm[8], ev[8];
    float lmax = -3e38f;
    #pragma unroll
    for (int k = 0; k < 8; ++k) {
        int t = k * 256 + tid;
        mv[k] = mb[b * TT + t];
        hm[k] = Hm[b * TT + t];
        if (hm[k] > 0.5f) lmax = fmaxf(lmax, mv[k]);
    }
    #pragma unroll
    for (int o = 32; o; o >>= 1) lmax = fmaxf(lmax, __shfl_xor(lmax, o));
    int wid = tid >> 6;
    if ((tid & 63) == 0) red[wid] = lmax;
    __syncthreads();
    lmax = fmaxf(fmaxf(red[0], red[1]), fmaxf(red[2], red[3]));
    float ls = 0.f;
    #pragma unroll
    for (int k = 0; k < 8; ++k) {
        ev[k] = (hm[k] > 0.5f) ? exp2f((mv[k] - lmax) * 1.44269504f) : 0.f;
        ls += ev[k];
    }
    #pragma unroll
    for (int o = 32; o; o >>= 1) ls += __shfl_xor(ls, o);
    if ((tid & 63) == 0) red[4 + wid] = ls;
    __syncthreads();
    float invs = 1.0f / (red[4] + red[5] + red[6] + red[7]);
    #pragma unroll
    for (int k = 0; k < 8; ++k) bvec[b * TT + k * 256 + tid] = ev[k] * invs;
    q2c_out[b * 256 + tid] = 0.f;   // must re-zero every launch (P2b accumulates)
}

// ---------------- P2b: q2c += sum_t bvec[t] * H[t,:]
__global__ __launch_bounds__(256) void p2b_q2c(
    const float* __restrict__ H, const float* __restrict__ bvec,
    float* __restrict__ q2c_out)
{
    const int b = blockIdx.x >> 4, ch = blockIdx.x & 15;
    const int tid = threadIdx.x, tq = tid >> 6, dq = tid & 63;
    const f32x4* H4 = (const f32x4*)H;
    f32x4 a = (f32x4)(0.0f);
    for (int tt = tq; tt < 128; tt += 4) {
        int t = ch * 128 + tt;
        float bv = bvec[b * TT + t];
        a += bv * H4[(b * TT + t) * 64 + dq];
    }
    __shared__ f32x4 red[4][64];
    red[tq][dq] = a;
    __syncthreads();
    if (tid < 64) {
        f32x4 s = red[0][tid] + red[1][tid] + red[2][tid] + red[3][tid];
        #pragma unroll
        for (int c = 0; c < 4; ++c) atomicAdd(&q2c_out[b * 256 + tid * 4 + c], s[c]);
    }
}

// ---------------- P3: G3 = H * q2c only (round-3 simple form)
__global__ __launch_bounds__(256) void p3_g3(
    const float* __restrict__ H, const float* __restrict__ q2c,
    float* __restrict__ Gout)
{
    int idx = blockIdx.x * 256 + threadIdx.x;   // over B*T*64 float4s
    int rowid = idx >> 6, c4 = idx & 63;
    int b = rowid >> 11;
    const f32x4* H4 = (const f32x4*)H;
    const f32x4* Q4 = (const f32x4*)q2c;
    f32x4* G4 = (f32x4*)Gout;
    f32x4 h4 = H4[idx];
    f32x4 q4 = Q4[b * 64 + c4];
    G4[rowid * 256 + 192 + c4] = h4 * q4;
}

extern "C" void kernel_launch(void* const* d_in, const int* in_sizes, int n_in,
                              void* d_out, int out_size, void* d_ws, size_t ws_size,
                              hipStream_t stream) {
    (void)in_sizes; (void)n_in; (void)out_size; (void)ws_size;
    const float* U    = (const float*)d_in[0];
    const float* H    = (const float*)d_in[1];
    const float* Um   = (const float*)d_in[2];
    const float* Hm   = (const float*)d_in[3];
    const float* w    = (const float*)d_in[4];
    const float* bias = (const float*)d_in[5];

    float* G   = (float*)d_out;
    float* c2q = G + (size_t)BB * TT * 1024;
    float* q2c = c2q + (size_t)BB * TT * 256;

    char* ws = (char*)d_ws;
    unsigned short* Ubf  = (unsigned short*)ws;                       // 4 MB
    unsigned short* UbfT = (unsigned short*)(ws + (4u << 20));        // 4 MB
    float* Uw   = (float*)(ws + (8u << 20));                          // 32 KB
    float* mb   = (float*)(ws + (8u << 20) + (64u << 10));            // 256 KB
    float* bvec = (float*)(ws + (8u << 20) + (320u << 10));           // 256 KB

    p0_prep<<<dim3(128), dim3(256), 0, stream>>>(U, w, Ubf, UbfT, Uw);
    p1_main<<<dim3(1024), dim3(256), 0, stream>>>(H, Um, w, bias, Ubf, UbfT, Uw, mb, G, c2q);
    p2a_bvec<<<dim3(32), dim3(256), 0, stream>>>(mb, Hm, bvec, q2c);
    p2b_q2c<<<dim3(512), dim3(256), 0, stream>>>(H, bvec, q2c);
    p3_g3<<<dim3(16384), dim3(256), 0, stream>>>(H, q2c, G);
}

// Round 9
// 152.298 us; speedup vs baseline: 6.4849x; 6.4849x over previous
//
#include <hip/hip_runtime.h>
#include <hip/hip_bf16.h>

#define BB 32
#define TT 2048
#define JJ 256
#define DD 256

typedef __attribute__((ext_vector_type(4))) float f32x4;
typedef __attribute__((ext_vector_type(2))) float f32x2;
typedef __attribute__((ext_vector_type(8))) short bf16x8;
typedef __attribute__((ext_vector_type(2))) unsigned int u32x2v;

static __device__ __forceinline__ unsigned short f2bf(float x) {
    unsigned u = __builtin_bit_cast(unsigned, x);
    u = (u + 0x7fffu + ((u >> 16) & 1u)) >> 16;
    return (unsigned short)u;
}
static __device__ __forceinline__ unsigned pack2(float a, float b) {
    return (unsigned)f2bf(a) | ((unsigned)f2bf(b) << 16);
}

// async 16B global->LDS stage of one 256-row x 32-k bf16 B-slice (16KB).
// Swizzle f(row) = (row>>1)&3: 4 distinct chunk-rotations per bank-parity class
// -> mm ds_read_b128 is 2-way (free) instead of 4-way (1.58x). Same involution
// on write-source and read side.
static __device__ __forceinline__ void stage_slice(
    const unsigned short* __restrict__ Bsrc, char* pool, int buf, int kt, int tid, int wid)
{
    #pragma unroll
    for (int it = 0; it < 4; ++it) {
        int s = it * 256 + tid;              // 16B-slot index 0..1023
        int row = s >> 2, cp = s & 3;
        int c = cp ^ ((row >> 1) & 3);       // pre-swizzled global source
        const char* src = (const char*)Bsrc + row * 512 + kt * 64 + c * 16;
        __builtin_amdgcn_global_load_lds(
            (const __attribute__((address_space(1))) unsigned int*)src,
            (__attribute__((address_space(3))) unsigned int*)(pool + (buf << 14) + (it << 12) + (wid << 10)),
            16, 0, 0);
    }
}

// ---------------- P0: U -> Ubf, UbfT, Uw = U.w_u; zeroes q2c (pre-atomics, every replay)
__global__ __launch_bounds__(256) void p0_prep(
    const float* __restrict__ U, const float* __restrict__ w,
    unsigned short* __restrict__ Ubf, unsigned short* __restrict__ UbfT,
    float* __restrict__ Uw, float* __restrict__ q2c_out)
{
    const int b = blockIdx.x >> 2, jc = blockIdx.x & 3;
    const int tid = threadIdx.x;
    if (jc == 0) q2c_out[b * 256 + tid] = 0.f;
    __shared__ unsigned short lt[64][258];
    const f32x4* U4 = (const f32x4*)U;
    const f32x4* W4 = (const f32x4*)w;
    for (int it = 0; it < 16; ++it) {
        int fi = it * 256 + tid;
        int lr = fi >> 6, c4 = fi & 63;
        int j = b * 256 + jc * 64 + lr;
        f32x4 u4 = U4[j * 64 + c4];
        unsigned short s0 = f2bf(u4[0]), s1 = f2bf(u4[1]), s2 = f2bf(u4[2]), s3 = f2bf(u4[3]);
        u32x2v pk; pk[0] = (unsigned)s0 | ((unsigned)s1 << 16); pk[1] = (unsigned)s2 | ((unsigned)s3 << 16);
        *(u32x2v*)(Ubf + j * 256 + c4 * 4) = pk;
        lt[lr][c4*4+0] = s0; lt[lr][c4*4+1] = s1; lt[lr][c4*4+2] = s2; lt[lr][c4*4+3] = s3;
        f32x4 wu = W4[64 + c4];
        float p = u4[0]*wu[0] + u4[1]*wu[1] + u4[2]*wu[2] + u4[3]*wu[3];
        #pragma unroll
        for (int o = 32; o; o >>= 1) p += __shfl_xor(p, o);
        if ((tid & 63) == 0) Uw[j] = p;
    }
    __syncthreads();
    for (int it2 = 0; it2 < 64; ++it2) {
        int d = it2 * 4 + (tid >> 6);
        int jl = tid & 63;
        UbfT[(b * 256 + d) * 256 + jc * 64 + jl] = lt[jl][d];
    }
}

// ---------------- P1: fused S -> masked softmax -> c2q; writes c2q, G0, G1, G2, mb
__global__ __launch_bounds__(256, 3) void p1_main(
    const float* __restrict__ H, const float* __restrict__ Um,
    const float* __restrict__ w, const float* __restrict__ biasp,
    const unsigned short* __restrict__ Ubf, const unsigned short* __restrict__ UbfT,
    const float* __restrict__ Uw,
    float* __restrict__ mb, float* __restrict__ Gout, float* __restrict__ c2q_out)
{
    // XCD-bijective swizzle: 1024 blocks = 8 XCDs x 128; each XCD owns 4 batches
    const int id = blockIdx.x;
    const int n = ((id & 7) << 7) | (id >> 3);
    const int b = n >> 5, tb = n & 31;
    const int t0 = tb * 64;
    const int tid = threadIdx.x;
    const int wid = tid >> 6, lane = tid & 63, g = lane >> 4, l16 = lane & 15;

    // pool phases: [hw 32KB] -> [B dbuf 2x16KB] -> [p_lds 4x9216] -> [B dbuf]
    __shared__ __align__(16) char pool[36864];
    __shared__ float uw_lds[256];
    __shared__ float um_lds[256];
    __shared__ float rt_lds[64];

    const f32x4* H4 = (const f32x4*)H;
    const f32x4* W4 = (const f32x4*)w;
    f32x4* G4 = (f32x4*)Gout;
    const float bias = biasp[0];
    const unsigned short* Ubf_b  = Ubf  + (size_t)b * 65536;
    const unsigned short* UbfT_b = UbfT + (size_t)b * 65536;

    uw_lds[tid] = Uw[b * 256 + tid];
    um_lds[tid] = Um[b * 256 + tid];

    // Phase A: stage Hw = H*w_hu into LDS (bf16, XOR-swizzled rows); rowterm = H.w_h; G0 = H
    for (int it = 0; it < 16; ++it) {
        int fi = it * 256 + tid;
        int lr = fi >> 6, c4 = fi & 63;
        f32x4 h4 = H4[(b * TT + t0 + lr) * 64 + c4];
        f32x4 whu = W4[128 + c4];
        f32x4 wh = W4[c4];
        G4[(b * TT + t0 + lr) * 256 + c4] = h4;          // G0 = H (coalesced f32x4)
        f32x4 hw = h4 * whu;
        u32x2v pk; pk[0] = pack2(hw[0], hw[1]); pk[1] = pack2(hw[2], hw[3]);
        unsigned off = ((unsigned)(lr * 512 + c4 * 8)) ^ ((unsigned)((lr & 7) << 4));
        *(u32x2v*)(pool + off) = pk;
        float p = h4[0]*wh[0] + h4[1]*wh[1] + h4[2]*wh[2] + h4[3]*wh[3];
        #pragma unroll
        for (int o = 32; o; o >>= 1) p += __shfl_xor(p, o);
        if (lane == 0) rt_lds[lr] = p;
    }
    __syncthreads();

    // A-frags (Hw rows of this wave) into registers
    bf16x8 af[8];
    {
        const int row = wid * 16 + l16;
        #pragma unroll
        for (int kt = 0; kt < 8; ++kt) {
            unsigned off = ((unsigned)(row * 512 + kt * 64 + g * 16)) ^ ((unsigned)((row & 7) << 4));
            af[kt] = *(const bf16x8*)(pool + off);
        }
    }
    __syncthreads();   // hw dead -> pool reused for B double-buffer

    // matmul1: S-core[t][j]; B = Ubf slices LDS-staged, double-buffered
    f32x4 acc[16];
    #pragma unroll
    for (int nt = 0; nt < 16; ++nt) acc[nt] = (f32x4)(0.0f);
    stage_slice(Ubf_b, pool, 0, 0, tid, wid);
    __syncthreads();                       // slice 0 resident
    #pragma unroll
    for (int kt = 0; kt < 8; ++kt) {
        if (kt < 7) stage_slice(Ubf_b, pool, (kt + 1) & 1, kt + 1, tid, wid);
        const char* bufp = pool + ((kt & 1) << 14);
        #pragma unroll
        for (int nt = 0; nt < 16; ++nt) {
            const int row = nt * 16 + l16;
            bf16x8 bfr = *(const bf16x8*)(bufp + row * 64 + ((g ^ ((row >> 1) & 3)) << 4));
            acc[nt] = __builtin_amdgcn_mfma_f32_16x16x32_bf16(af[kt], bfr, acc[nt], 0, 0, 0);
        }
        __syncthreads();                   // drains next-slice stage + compute reads
    }

    // masked softmax over j (rowterm+bias are shift-invariant; added only to mb)
    float rmax[4] = {-3e38f, -3e38f, -3e38f, -3e38f};
    #pragma unroll
    for (int nt = 0; nt < 16; ++nt) {
        float ct = uw_lds[nt * 16 + l16];
        float msk = um_lds[nt * 16 + l16];
        #pragma unroll
        for (int r = 0; r < 4; ++r) {
            float v = acc[nt][r] + ct;
            acc[nt][r] = v;
            if (msk > 0.5f) rmax[r] = fmaxf(rmax[r], v);
        }
    }
    #pragma unroll
    for (int r = 0; r < 4; ++r) {
        #pragma unroll
        for (int o = 1; o < 16; o <<= 1) rmax[r] = fmaxf(rmax[r], __shfl_xor(rmax[r], o));
    }
    float rsum[4] = {0.f, 0.f, 0.f, 0.f};
    #pragma unroll
    for (int nt = 0; nt < 16; ++nt) {
        float msk = um_lds[nt * 16 + l16];
        #pragma unroll
        for (int r = 0; r < 4; ++r) {
            float e = (msk > 0.5f) ? exp2f((acc[nt][r] - rmax[r]) * 1.44269504f) : 0.0f;
            acc[nt][r] = e;
            rsum[r] += e;
        }
    }
    #pragma unroll
    for (int r = 0; r < 4; ++r) {
        #pragma unroll
        for (int o = 1; o < 16; o <<= 1) rsum[r] += __shfl_xor(rsum[r], o);
    }
    if (l16 == 0) {
        #pragma unroll
        for (int r = 0; r < 4; ++r) {
            int lrow = wid * 16 + g * 4 + r;
            mb[b * TT + t0 + lrow] = rmax[r] + rt_lds[lrow] + bias;
        }
    }
    float inv[4];
    #pragma unroll
    for (int r = 0; r < 4; ++r) inv[r] = 1.0f / rsum[r];

    // write P^T to LDS: p_lds[wave][j][t], 36B j-rows (9j mod 32 is a permutation -> ~conflict-free)
    const unsigned wb = (unsigned)wid * 9216u;
    #pragma unroll
    for (int nt = 0; nt < 16; ++nt) {
        int j = nt * 16 + l16;
        unsigned lo = pack2(acc[nt][0] * inv[0], acc[nt][1] * inv[1]);
        unsigned hi = pack2(acc[nt][2] * inv[2], acc[nt][3] * inv[3]);
        char* p = pool + wb + (unsigned)(j * 36) + (unsigned)(g * 8);
        *(unsigned*)(p) = lo;
        *(unsigned*)(p + 4) = hi;
    }
    // per-wave region: no barrier needed between own writes and own reads (lgkm ordering)
    bf16x8 pa[8];
    #pragma unroll
    for (int kt = 0; kt < 8; ++kt) {
        #pragma unroll
        for (int jj = 0; jj < 8; ++jj) {
            int j = kt * 32 + g * 8 + jj;
            unsigned short pv = *(const unsigned short*)(pool + wb + (unsigned)(j * 36) + (unsigned)(l16 * 2));
            pa[kt][jj] = (short)pv;
        }
    }
    __syncthreads();   // all pa extracted -> pool reusable for B double-buffer

    // matmul2: c2q[t][d]; B = UbfT slices LDS-staged, double-buffered
    f32x4 acc2[16];
    #pragma unroll
    for (int nt = 0; nt < 16; ++nt) acc2[nt] = (f32x4)(0.0f);
    stage_slice(UbfT_b, pool, 0, 0, tid, wid);
    __syncthreads();
    #pragma unroll
    for (int kt = 0; kt < 8; ++kt) {
        if (kt < 7) stage_slice(UbfT_b, pool, (kt + 1) & 1, kt + 1, tid, wid);
        const char* bufp = pool + ((kt & 1) << 14);
        #pragma unroll
        for (int nt = 0; nt < 16; ++nt) {
            const int row = nt * 16 + l16;
            bf16x8 bfr = *(const bf16x8*)(bufp + row * 64 + ((g ^ ((row >> 1) & 3)) << 4));
            acc2[nt] = __builtin_amdgcn_mfma_f32_16x16x32_bf16(pa[kt], bfr, acc2[nt], 0, 0, 0);
        }
        __syncthreads();
    }

    // epilogue: c2q, G1 = c2q, G2 = H*c2q — pair-merged stores:
    // even l16 stores the (d,d+1) pair of nt=2m; odd l16 the (d-1,d) pair of nt=2m+1.
    // All 64 lanes active, 8B/lane, 512B/instruction; values bit-identical to scalar form.
    {
        const bool odd = (l16 & 1) != 0;
        #pragma unroll
        for (int m = 0; m < 8; ++m) {
            const int dA = (2 * m) * 16 + l16;          // even-lane pair base
            const int dB = (2 * m + 1) * 16 + l16 - 1;  // odd-lane pair base
            const int d0 = odd ? dB : dA;
            #pragma unroll
            for (int r = 0; r < 4; ++r) {
                float cA = acc2[2 * m][r];
                float cB = acc2[2 * m + 1][r];
                float sA = __shfl_xor(cA, 1);
                float sB = __shfl_xor(cB, 1);
                f32x2 cp;
                cp[0] = odd ? sB : cA;
                cp[1] = odd ? cB : sA;
                int t = t0 + wid * 16 + g * 4 + r;
                const float* hrow = H + (b * TT + t) * 256;
                f32x2 h2 = *(const f32x2*)(hrow + d0);
                float* grow = Gout + (size_t)(b * TT + t) * 1024;
                *(f32x2*)(grow + 256 + d0) = cp;
                *(f32x2*)(grow + 512 + d0) = h2 * cp;
                *(f32x2*)(c2q_out + (size_t)(b * TT + t) * 256 + d0) = cp;
            }
        }
    }
}

// ---------------- P2 (fused): recompute b-softmax normalizer from mb, then q2c chunk-reduce
__global__ __launch_bounds__(256) void p2_fused(
    const float* __restrict__ mb, const float* __restrict__ Hm,
    const float* __restrict__ H, float* __restrict__ q2c_out)
{
    const int b = blockIdx.x >> 4, ch = blockIdx.x & 15;
    const int tid = threadIdx.x;
    __shared__ float red[8];
    float mv[8], hm[8];
    float lmax = -3e38f;
    #pragma unroll
    for (int k = 0; k < 8; ++k) {
        int t = k * 256 + tid;
        mv[k] = mb[b * TT + t];
        hm[k] = Hm[b * TT + t];
        if (hm[k] > 0.5f) lmax = fmaxf(lmax, mv[k]);
    }
    #pragma unroll
    for (int o = 32; o; o >>= 1) lmax = fmaxf(lmax, __shfl_xor(lmax, o));
    int wv = tid >> 6;
    if ((tid & 63) == 0) red[wv] = lmax;
    __syncthreads();
    lmax = fmaxf(fmaxf(red[0], red[1]), fmaxf(red[2], red[3]));
    float ls = 0.f;
    #pragma unroll
    for (int k = 0; k < 8; ++k)
        ls += (hm[k] > 0.5f) ? exp2f((mv[k] - lmax) * 1.44269504f) : 0.f;
    #pragma unroll
    for (int o = 32; o; o >>= 1) ls += __shfl_xor(ls, o);
    if ((tid & 63) == 0) red[4 + wv] = ls;
    __syncthreads();
    const float invs = 1.0f / (red[4] + red[5] + red[6] + red[7] + 1e-13f);

    // chunk reduce: q2c += sum_{t in chunk} bvec[t] * H[t,:]
    const int tq = tid >> 6, dq = tid & 63;
    const f32x4* H4 = (const f32x4*)H;
    f32x4 a = (f32x4)(0.0f);
    for (int tt = tq; tt < 128; tt += 4) {
        int t = ch * 128 + tt;
        float bm = mb[b * TT + t];
        float hmv = Hm[b * TT + t];
        float bv = (hmv > 0.5f) ? exp2f((bm - lmax) * 1.44269504f) * invs : 0.f;
        a += bv * H4[(b * TT + t) * 64 + dq];
    }
    __shared__ f32x4 red4[4][64];
    red4[tq][dq] = a;
    __syncthreads();
    if (tid < 64) {
        f32x4 s = red4[0][tid] + red4[1][tid] + red4[2][tid] + red4[3][tid];
        #pragma unroll
        for (int c = 0; c < 4; ++c) atomicAdd(&q2c_out[b * 256 + tid * 4 + c], s[c]);
    }
}

// ---------------- P3: G3 = H * q2c only (round-3 simple form)
__global__ __launch_bounds__(256) void p3_g3(
    const float* __restrict__ H, const float* __restrict__ q2c,
    float* __restrict__ Gout)
{
    int idx = blockIdx.x * 256 + threadIdx.x;   // over B*T*64 float4s
    int rowid = idx >> 6, c4 = idx & 63;
    int b = rowid >> 11;
    const f32x4* H4 = (const f32x4*)H;
    const f32x4* Q4 = (const f32x4*)q2c;
    f32x4* G4 = (f32x4*)Gout;
    f32x4 h4 = H4[idx];
    f32x4 q4 = Q4[b * 64 + c4];
    G4[rowid * 256 + 192 + c4] = h4 * q4;
}

extern "C" void kernel_launch(void* const* d_in, const int* in_sizes, int n_in,
                              void* d_out, int out_size, void* d_ws, size_t ws_size,
                              hipStream_t stream) {
    (void)in_sizes; (void)n_in; (void)out_size; (void)ws_size;
    const float* U    = (const float*)d_in[0];
    const float* H    = (const float*)d_in[1];
    const float* Um   = (const float*)d_in[2];
    const float* Hm   = (const float*)d_in[3];
    const float* w    = (const float*)d_in[4];
    const float* bias = (const float*)d_in[5];

    float* G   = (float*)d_out;
    float* c2q = G + (size_t)BB * TT * 1024;
    float* q2c = c2q + (size_t)BB * TT * 256;

    char* ws = (char*)d_ws;
    unsigned short* Ubf  = (unsigned short*)ws;                       // 4 MB
    unsigned short* UbfT = (unsigned short*)(ws + (4u << 20));        // 4 MB
    float* Uw   = (float*)(ws + (8u << 20));                          // 32 KB
    float* mb   = (float*)(ws + (8u << 20) + (64u << 10));            // 256 KB

    p0_prep<<<dim3(128), dim3(256), 0, stream>>>(U, w, Ubf, UbfT, Uw, q2c);
    p1_main<<<dim3(1024), dim3(256), 0, stream>>>(H, Um, w, bias, Ubf, UbfT, Uw, mb, G, c2q);
    p2_fused<<<dim3(512), dim3(256), 0, stream>>>(mb, Hm, H, q2c);
    p3_g3<<<dim3(16384), dim3(256), 0, stream>>>(H, q2c, G);
}

// Round 10
// 145.578 us; speedup vs baseline: 6.7843x; 1.0462x over previous
//
#include <hip/hip_runtime.h>
#include <hip/hip_bf16.h>

#define BB 32
#define TT 2048
#define JJ 256
#define DD 256

typedef __attribute__((ext_vector_type(4))) float f32x4;
typedef __attribute__((ext_vector_type(8))) short bf16x8;
typedef __attribute__((ext_vector_type(2))) unsigned int u32x2v;

static __device__ __forceinline__ unsigned short f2bf(float x) {
    unsigned u = __builtin_bit_cast(unsigned, x);
    u = (u + 0x7fffu + ((u >> 16) & 1u)) >> 16;
    return (unsigned short)u;
}
static __device__ __forceinline__ unsigned pack2(float a, float b) {
    return (unsigned)f2bf(a) | ((unsigned)f2bf(b) << 16);
}

// async 16B global->LDS stage of one 256-row x 32-k bf16 B-slice (16KB).
// Swizzle f(row)=(row>>1)&3: 4 distinct chunk rotations per bank-parity class
// -> mm ds_read_b128 2-way (free) instead of 4-way. Same involution both sides.
static __device__ __forceinline__ void stage_slice(
    const unsigned short* __restrict__ Bsrc, char* pool, int buf, int kt, int tid, int wid)
{
    #pragma unroll
    for (int it = 0; it < 4; ++it) {
        int s = it * 256 + tid;              // 16B-slot index 0..1023
        int row = s >> 2, cp = s & 3;
        int c = cp ^ ((row >> 1) & 3);       // pre-swizzled global source
        const char* src = (const char*)Bsrc + row * 512 + kt * 64 + c * 16;
        __builtin_amdgcn_global_load_lds(
            (const __attribute__((address_space(1))) unsigned int*)src,
            (__attribute__((address_space(3))) unsigned int*)(pool + (buf << 14) + (it << 12) + (wid << 10)),
            16, 0, 0);
    }
}

// ---------------- P0: U -> Ubf (row-major bf16), UbfT (transposed bf16), Uw = U.w_u (f32)
__global__ __launch_bounds__(256) void p0_prep(
    const float* __restrict__ U, const float* __restrict__ w,
    unsigned short* __restrict__ Ubf, unsigned short* __restrict__ UbfT,
    float* __restrict__ Uw)
{
    const int b = blockIdx.x >> 2, jc = blockIdx.x & 3;
    const int tid = threadIdx.x;
    __shared__ unsigned short lt[64][258];
    const f32x4* U4 = (const f32x4*)U;
    const f32x4* W4 = (const f32x4*)w;
    for (int it = 0; it < 16; ++it) {
        int fi = it * 256 + tid;
        int lr = fi >> 6, c4 = fi & 63;
        int j = b * 256 + jc * 64 + lr;
        f32x4 u4 = U4[j * 64 + c4];
        unsigned short s0 = f2bf(u4[0]), s1 = f2bf(u4[1]), s2 = f2bf(u4[2]), s3 = f2bf(u4[3]);
        u32x2v pk; pk[0] = (unsigned)s0 | ((unsigned)s1 << 16); pk[1] = (unsigned)s2 | ((unsigned)s3 << 16);
        *(u32x2v*)(Ubf + j * 256 + c4 * 4) = pk;
        lt[lr][c4*4+0] = s0; lt[lr][c4*4+1] = s1; lt[lr][c4*4+2] = s2; lt[lr][c4*4+3] = s3;
        f32x4 wu = W4[64 + c4];
        float p = u4[0]*wu[0] + u4[1]*wu[1] + u4[2]*wu[2] + u4[3]*wu[3];
        #pragma unroll
        for (int o = 32; o; o >>= 1) p += __shfl_xor(p, o);
        if ((tid & 63) == 0) Uw[j] = p;
    }
    __syncthreads();
    for (int it2 = 0; it2 < 64; ++it2) {
        int d = it2 * 4 + (tid >> 6);
        int jl = tid & 63;
        UbfT[(b * 256 + d) * 256 + jc * 64 + jl] = lt[jl][d];
    }
}

// ---------------- P1: fused S -> masked softmax -> c2q; writes c2q, G0, G1, G2, mb
// Round-3 structure (best measured): scalar epilogue, plain stores, bounds(256,3).
__global__ __launch_bounds__(256, 3) void p1_main(
    const float* __restrict__ H, const float* __restrict__ Um,
    const float* __restrict__ w, const float* __restrict__ biasp,
    const unsigned short* __restrict__ Ubf, const unsigned short* __restrict__ UbfT,
    const float* __restrict__ Uw,
    float* __restrict__ mb, float* __restrict__ Gout, float* __restrict__ c2q_out)
{
    // XCD-bijective swizzle: 1024 blocks = 8 XCDs x 128; each XCD owns 4 batches
    const int id = blockIdx.x;
    const int n = ((id & 7) << 7) | (id >> 3);
    const int b = n >> 5, tb = n & 31;
    const int t0 = tb * 64;
    const int tid = threadIdx.x;
    const int wid = tid >> 6, lane = tid & 63, g = lane >> 4, l16 = lane & 15;

    // pool phases: [hw 32KB] -> [B dbuf 2x16KB] -> [p_lds 4x9216] -> [B dbuf]
    __shared__ __align__(16) char pool[36864];
    __shared__ float uw_lds[256];
    __shared__ float um_lds[256];
    __shared__ float rt_lds[64];

    const f32x4* H4 = (const f32x4*)H;
    const f32x4* W4 = (const f32x4*)w;
    f32x4* G4 = (f32x4*)Gout;
    const float bias = biasp[0];
    const unsigned short* Ubf_b  = Ubf  + (size_t)b * 65536;
    const unsigned short* UbfT_b = UbfT + (size_t)b * 65536;

    uw_lds[tid] = Uw[b * 256 + tid];
    um_lds[tid] = Um[b * 256 + tid];

    // Phase A: stage Hw = H*w_hu into LDS (bf16, XOR-swizzled rows); rowterm = H.w_h; G0 = H
    for (int it = 0; it < 16; ++it) {
        int fi = it * 256 + tid;
        int lr = fi >> 6, c4 = fi & 63;
        f32x4 h4 = H4[(b * TT + t0 + lr) * 64 + c4];
        f32x4 whu = W4[128 + c4];
        f32x4 wh = W4[c4];
        G4[(b * TT + t0 + lr) * 256 + c4] = h4;          // G0 = H (coalesced f32x4)
        f32x4 hw = h4 * whu;
        u32x2v pk; pk[0] = pack2(hw[0], hw[1]); pk[1] = pack2(hw[2], hw[3]);
        unsigned off = ((unsigned)(lr * 512 + c4 * 8)) ^ ((unsigned)((lr & 7) << 4));
        *(u32x2v*)(pool + off) = pk;
        float p = h4[0]*wh[0] + h4[1]*wh[1] + h4[2]*wh[2] + h4[3]*wh[3];
        #pragma unroll
        for (int o = 32; o; o >>= 1) p += __shfl_xor(p, o);
        if (lane == 0) rt_lds[lr] = p;
    }
    __syncthreads();

    // A-frags (Hw rows of this wave) into registers
    bf16x8 af[8];
    {
        const int row = wid * 16 + l16;
        #pragma unroll
        for (int kt = 0; kt < 8; ++kt) {
            unsigned off = ((unsigned)(row * 512 + kt * 64 + g * 16)) ^ ((unsigned)((row & 7) << 4));
            af[kt] = *(const bf16x8*)(pool + off);
        }
    }
    __syncthreads();   // hw dead -> pool reused for B double-buffer

    // matmul1: S-core[t][j]; B = Ubf slices LDS-staged, double-buffered
    f32x4 acc[16];
    #pragma unroll
    for (int nt = 0; nt < 16; ++nt) acc[nt] = (f32x4)(0.0f);
    stage_slice(Ubf_b, pool, 0, 0, tid, wid);
    __syncthreads();                       // slice 0 resident
    #pragma unroll
    for (int kt = 0; kt < 8; ++kt) {
        if (kt < 7) stage_slice(Ubf_b, pool, (kt + 1) & 1, kt + 1, tid, wid);
        const char* bufp = pool + ((kt & 1) << 14);
        #pragma unroll
        for (int nt = 0; nt < 16; ++nt) {
            const int row = nt * 16 + l16;
            bf16x8 bfr = *(const bf16x8*)(bufp + row * 64 + ((g ^ ((row >> 1) & 3)) << 4));
            acc[nt] = __builtin_amdgcn_mfma_f32_16x16x32_bf16(af[kt], bfr, acc[nt], 0, 0, 0);
        }
        __syncthreads();                   // drains next-slice stage + compute reads
    }

    // masked softmax over j (rowterm+bias are shift-invariant; added only to mb)
    float rmax[4] = {-3e38f, -3e38f, -3e38f, -3e38f};
    #pragma unroll
    for (int nt = 0; nt < 16; ++nt) {
        float ct = uw_lds[nt * 16 + l16];
        float msk = um_lds[nt * 16 + l16];
        #pragma unroll
        for (int r = 0; r < 4; ++r) {
            float v = acc[nt][r] + ct;
            acc[nt][r] = v;
            if (msk > 0.5f) rmax[r] = fmaxf(rmax[r], v);
        }
    }
    #pragma unroll
    for (int r = 0; r < 4; ++r) {
        #pragma unroll
        for (int o = 1; o < 16; o <<= 1) rmax[r] = fmaxf(rmax[r], __shfl_xor(rmax[r], o));
    }
    float rsum[4] = {0.f, 0.f, 0.f, 0.f};
    #pragma unroll
    for (int nt = 0; nt < 16; ++nt) {
        float msk = um_lds[nt * 16 + l16];
        #pragma unroll
        for (int r = 0; r < 4; ++r) {
            float e = (msk > 0.5f) ? exp2f((acc[nt][r] - rmax[r]) * 1.44269504f) : 0.0f;
            acc[nt][r] = e;
            rsum[r] += e;
        }
    }
    #pragma unroll
    for (int r = 0; r < 4; ++r) {
        #pragma unroll
        for (int o = 1; o < 16; o <<= 1) rsum[r] += __shfl_xor(rsum[r], o);
    }
    if (l16 == 0) {
        #pragma unroll
        for (int r = 0; r < 4; ++r) {
            int lrow = wid * 16 + g * 4 + r;
            mb[b * TT + t0 + lrow] = rmax[r] + rt_lds[lrow] + bias;
        }
    }
    float inv[4];
    #pragma unroll
    for (int r = 0; r < 4; ++r) inv[r] = 1.0f / rsum[r];

    // write P^T to LDS: p_lds[wave][j][t], 36B j-rows (9j mod 32 is a permutation -> ~conflict-free)
    const unsigned wb = (unsigned)wid * 9216u;
    #pragma unroll
    for (int nt = 0; nt < 16; ++nt) {
        int j = nt * 16 + l16;
        unsigned lo = pack2(acc[nt][0] * inv[0], acc[nt][1] * inv[1]);
        unsigned hi = pack2(acc[nt][2] * inv[2], acc[nt][3] * inv[3]);
        char* p = pool + wb + (unsigned)(j * 36) + (unsigned)(g * 8);
        *(unsigned*)(p) = lo;
        *(unsigned*)(p + 4) = hi;
    }
    // per-wave region: no barrier needed between own writes and own reads (lgkm ordering)
    bf16x8 pa[8];
    #pragma unroll
    for (int kt = 0; kt < 8; ++kt) {
        #pragma unroll
        for (int jj = 0; jj < 8; ++jj) {
            int j = kt * 32 + g * 8 + jj;
            unsigned short pv = *(const unsigned short*)(pool + wb + (unsigned)(j * 36) + (unsigned)(l16 * 2));
            pa[kt][jj] = (short)pv;
        }
    }
    __syncthreads();   // all pa extracted -> pool reusable for B double-buffer

    // matmul2: c2q[t][d]; B = UbfT slices LDS-staged, double-buffered
    f32x4 acc2[16];
    #pragma unroll
    for (int nt = 0; nt < 16; ++nt) acc2[nt] = (f32x4)(0.0f);
    stage_slice(UbfT_b, pool, 0, 0, tid, wid);
    __syncthreads();
    #pragma unroll
    for (int kt = 0; kt < 8; ++kt) {
        if (kt < 7) stage_slice(UbfT_b, pool, (kt + 1) & 1, kt + 1, tid, wid);
        const char* bufp = pool + ((kt & 1) << 14);
        #pragma unroll
        for (int nt = 0; nt < 16; ++nt) {
            const int row = nt * 16 + l16;
            bf16x8 bfr = *(const bf16x8*)(bufp + row * 64 + ((g ^ ((row >> 1) & 3)) << 4));
            acc2[nt] = __builtin_amdgcn_mfma_f32_16x16x32_bf16(pa[kt], bfr, acc2[nt], 0, 0, 0);
        }
        __syncthreads();
    }

    // epilogue: c2q, G1 = c2q, G2 = H*c2q (round-3 scalar form, plain stores)
    #pragma unroll
    for (int nt = 0; nt < 16; ++nt) {
        int d = nt * 16 + l16;
        #pragma unroll
        for (int r = 0; r < 4; ++r) {
            int t = t0 + wid * 16 + g * 4 + r;
            float c = acc2[nt][r];
            float h = H[(b * TT + t) * 256 + d];
            int gbase = (b * TT + t) * 1024;
            Gout[gbase + 256 + d] = c;
            Gout[gbase + 512 + d] = h * c;
            c2q_out[(b * TT + t) * 256 + d] = c;
        }
    }
}

// ---------------- P2a: b_vec = masked softmax(mb, H_mask); zero q2c
__global__ __launch_bounds__(256) void p2a_bvec(
    const float* __restrict__ mb, const float* __restrict__ Hm,
    float* __restrict__ bvec, float* __restrict__ q2c_out)
{
    const int b = blockIdx.x, tid = threadIdx.x;
    __shared__ float red[8];
    float mv[8], hm[8], ev[8];
    float lmax = -3e38f;
    #pragma unroll
    for (int k = 0; k < 8; ++k) {
        int t = k * 256 + tid;
        mv[k] = mb[b * TT + t];
        hm[k] = Hm[b * TT + t];
        if (hm[k] > 0.5f) lmax = fmaxf(lmax, mv[k]);
    }
    #pragma unroll
    for (int o = 32; o; o >>= 1) lmax = fmaxf(lmax, __shfl_xor(lmax, o));
    int wid = tid >> 6;
    if ((tid & 63) == 0) red[wid] = lmax;
    __syncthreads();
    lmax = fmaxf(fmaxf(red[0], red[1]), fmaxf(red[2], red[3]));
    float ls = 0.f;
    #pragma unroll
    for (int k = 0; k < 8; ++k) {
        ev[k] = (hm[k] > 0.5f) ? exp2f((mv[k] - lmax) * 1.44269504f) : 0.f;
        ls += ev[k];
    }
    #pragma unroll
    for (int o = 32; o; o >>= 1) ls += __shfl_xor(ls, o);
    if ((tid & 63) == 0) red[4 + wid] = ls;
    __syncthreads();
    float invs = 1.0f / (red[4] + red[5] + red[6] + red[7]);
    #pragma unroll
    for (int k = 0; k < 8; ++k) bvec[b * TT + k * 256 + tid] = ev[k] * invs;
    q2c_out[b * 256 + tid] = 0.f;   // must re-zero every launch (P2b accumulates)
}

// ---------------- P2b: q2c += sum_t bvec[t] * H[t,:]
__global__ __launch_bounds__(256) void p2b_q2c(
    const float* __restrict__ H, const float* __restrict__ bvec,
    float* __restrict__ q2c_out)
{
    const int b = blockIdx.x >> 4, ch = blockIdx.x & 15;
    const int tid = threadIdx.x, tq = tid >> 6, dq = tid & 63;
    const f32x4* H4 = (const f32x4*)H;
    f32x4 a = (f32x4)(0.0f);
    for (int tt = tq; tt < 128; tt += 4) {
        int t = ch * 128 + tt;
        float bv = bvec[b * TT + t];
        a += bv * H4[(b * TT + t) * 64 + dq];
    }
    __shared__ f32x4 red[4][64];
    red[tq][dq] = a;
    __syncthreads();
    if (tid < 64) {
        f32x4 s = red[0][tid] + red[1][tid] + red[2][tid] + red[3][tid];
        #pragma unroll
        for (int c = 0; c < 4; ++c) atomicAdd(&q2c_out[b * 256 + tid * 4 + c], s[c]);
    }
}

// ---------------- P3: G3 = H * q2c only (round-3 simple form)
__global__ __launch_bounds__(256) void p3_g3(
    const float* __restrict__ H, const float* __restrict__ q2c,
    float* __restrict__ Gout)
{
    int idx = blockIdx.x * 256 + threadIdx.x;   // over B*T*64 float4s
    int rowid = idx >> 6, c4 = idx & 63;
    int b = rowid >> 11;
    const f32x4* H4 = (const f32x4*)H;
    const f32x4* Q4 = (const f32x4*)q2c;
    f32x4* G4 = (f32x4*)Gout;
    f32x4 h4 = H4[idx];
    f32x4 q4 = Q4[b * 64 + c4];
    G4[rowid * 256 + 192 + c4] = h4 * q4;
}

extern "C" void kernel_launch(void* const* d_in, const int* in_sizes, int n_in,
                              void* d_out, int out_size, void* d_ws, size_t ws_size,
                              hipStream_t stream) {
    (void)in_sizes; (void)n_in; (void)out_size; (void)ws_size;
    const float* U    = (const float*)d_in[0];
    const float* H    = (const float*)d_in[1];
    const float* Um   = (const float*)d_in[2];
    const float* Hm   = (const float*)d_in[3];
    const float* w    = (const float*)d_in[4];
    const float* bias = (const float*)d_in[5];

    float* G   = (float*)d_out;
    float* c2q = G + (size_t)BB * TT * 1024;
    float* q2c = c2q + (size_t)BB * TT * 256;

    char* ws = (char*)d_ws;
    unsigned short* Ubf  = (unsigned short*)ws;                       // 4 MB
    unsigned short* UbfT = (unsigned short*)(ws + (4u << 20));        // 4 MB
    float* Uw   = (float*)(ws + (8u << 20));                          // 32 KB
    float* mb   = (float*)(ws + (8u << 20) + (64u << 10));            // 256 KB
    float* bvec = (float*)(ws + (8u << 20) + (320u << 10));           // 256 KB

    p0_prep<<<dim3(128), dim3(256), 0, stream>>>(U, w, Ubf, UbfT, Uw);
    p1_main<<<dim3(1024), dim3(256), 0, stream>>>(H, Um, w, bias, Ubf, UbfT, Uw, mb, G, c2q);
    p2a_bvec<<<dim3(32), dim3(256), 0, stream>>>(mb, Hm, bvec, q2c);
    p2b_q2c<<<dim3(512), dim3(256), 0, stream>>>(H, bvec, q2c);
    p3_g3<<<dim3(16384), dim3(256), 0, stream>>>(H, q2c, G);
}